// Round 1
// baseline (335.227 us; speedup 1.0000x reference)
//
#include <hip/hip_runtime.h>
#include <stdint.h>

#define HW 16384
#define Bn 16
#define Ln 24
#define Dn 256
#define Qn 256
#define Cn 256

typedef __attribute__((ext_vector_type(8))) short short8;
typedef __attribute__((ext_vector_type(4))) float f32x4;

__device__ __forceinline__ unsigned short f2bf(float f) {
  unsigned u = __builtin_bit_cast(unsigned, f);
  u += 0x7FFFu + ((u >> 16) & 1u);
  return (unsigned short)(u >> 16);
}
__device__ __forceinline__ float bf2f(unsigned short s) {
  return __builtin_bit_cast(float, (unsigned)s << 16);
}

__device__ __forceinline__ void gl_lds16(const void* gsrc, void* lds) {
  __builtin_amdgcn_global_load_lds(
      (const __attribute__((address_space(1))) unsigned int*)gsrc,
      (__attribute__((address_space(3))) unsigned int*)lds, 16, 0, 0);
}

// ---------------- kernel 1: k[b,l,q] = w_src[b,l,:]·fck_w[q,:] + fck_b[q] ----
__global__ void k_keys(const float* __restrict__ wsrc, const float* __restrict__ fckw,
                       const float* __restrict__ fckb, float* __restrict__ kmat) {
  int b = blockIdx.x / Ln, l = blockIdx.x % Ln;
  __shared__ float row[Dn];
  row[threadIdx.x] = wsrc[(b * Ln + l) * Dn + threadIdx.x];
  __syncthreads();
  int q = threadIdx.x;
  const float* wq = fckw + q * Dn;
  float acc = fckb[q];
#pragma unroll 8
  for (int d = 0; d < Dn; ++d) acc += row[d] * wq[d];
  kmat[(b * Ln + l) * Qn + q] = acc;
}

// ---------------- kernel 2: scores/argmax/w_alloc/bias0 ----------------------
__global__ void k_alloc(const float* __restrict__ wsrc, const float* __restrict__ wtgt,
                        const float* __restrict__ conv0b, const float* __restrict__ kmat,
                        float* __restrict__ walloc, float* __restrict__ bias0) {
  int b = blockIdx.x;
  __shared__ float S[Ln][Dn];
  __shared__ float T[Ln][Dn];
  __shared__ double sc[Ln][Ln];
  __shared__ double cs[Ln];
  __shared__ int idx[Ln];
  int tid = threadIdx.x;
  for (int n = tid; n < Ln * Dn; n += 256) {
    S[n >> 8][n & 255] = wsrc[b * Ln * Dn + n];
    T[n >> 8][n & 255] = wtgt[b * Ln * Dn + n];
  }
  __syncthreads();
  for (int p = tid; p < Ln * Ln; p += 256) {
    int l = p / Ln, m = p % Ln;
    double a = 0.0;
    for (int d = 0; d < Dn; ++d) a += (double)S[l][d] * (double)T[m][d];
    sc[l][m] = a;
  }
  __syncthreads();
  if (tid < Ln) {
    double a = 0.0;
    for (int l = 0; l < Ln; ++l) a += sc[l][tid];
    cs[tid] = a;
  }
  __syncthreads();
  if (tid < Ln) {
    double best = -1e300; int bi = 0;
    for (int m = 0; m < Ln; ++m) {
      double v = cs[m] - sc[tid][m];
      if (v > best) { best = v; bi = m; }
    }
    idx[tid] = bi;
  }
  __syncthreads();
  for (int n = tid; n < Ln * Dn; n += 256) {
    int l = n >> 8, d = n & 255;
    walloc[b * Ln * Dn + n] = T[idx[l]][d];
  }
  if (tid < Ln) {
    float a = 0.f;
    const float* kr = kmat + (b * Ln + tid) * Qn;
    for (int q = 0; q < Qn; ++q) a += conv0b[q] * kr[q];
    bias0[b * Ln + tid] = a;
  }
}

// ---------------- kernel 3: M[b,l,c] and bg[b,l,e] ---------------------------
__global__ void k_mbg(const float* __restrict__ kmat, const float* __restrict__ conv0w,
                      const float* __restrict__ walloc, const float* __restrict__ fcw,
                      const float* __restrict__ fcb,
                      float* __restrict__ Mmat, float* __restrict__ bg) {
  int bid = blockIdx.x;
  __shared__ float row[Dn];
  if (bid < Bn * Ln) {
    int b = bid / Ln, l = bid % Ln;
    row[threadIdx.x] = kmat[(b * Ln + l) * Qn + threadIdx.x];
    __syncthreads();
    int c = threadIdx.x;
    float acc = 0.f;
    for (int q = 0; q < Qn; ++q) acc += row[q] * conv0w[q * Cn + c];
    Mmat[(b * Ln + l) * Cn + c] = acc;
  } else {
    int id = bid - Bn * Ln;
    int b = id / Ln, l = id % Ln;
    row[threadIdx.x] = walloc[(b * Ln + l) * Dn + threadIdx.x];
    __syncthreads();
    for (int it = 0; it < 2; ++it) {
      int e = it * 256 + threadIdx.x;
      const float* we = fcw + e * Dn;
      float acc = fcb[e];
      for (int d = 0; d < Dn; ++d) acc += row[d] * we[d];
      bg[(b * Ln + l) * (2 * Cn) + e] = acc;
    }
  }
}

// ---------------- kernel 4: G blobs (pre-swizzled LDS images) + bv -----------
// blob(b,g,t)[16KB]: rows m in [0,128): m<64 -> gamma col c_out=g*64+m (bg col 256+c_out)
//                                      m>=64 -> beta  col c_out=g*64+m-64 (bg col c_out)
// byte off(m,k) = (m*128 + k*2) ^ ((m&7)<<4), value = sum_l M[b,l,t*64+k]*gb
__global__ void k_gbuild(const float* __restrict__ Mmat, const float* __restrict__ bg,
                         const float* __restrict__ bias0,
                         unsigned short* __restrict__ Gt, float* __restrict__ bv) {
  int t = blockIdx.x, g = blockIdx.y, b = blockIdx.z;
  __shared__ float Ms[Ln][64];
  __shared__ float Gb[Ln][128];
  __shared__ float B0[Ln];
  __shared__ __align__(16) unsigned char img[16384];
  int tid = threadIdx.x;
  for (int n = tid; n < Ln * 64; n += 256) {
    int l = n >> 6, kk = n & 63;
    Ms[l][kk] = Mmat[(b * Ln + l) * Cn + t * 64 + kk];
  }
  for (int n = tid; n < Ln * 128; n += 256) {
    int l = n >> 7, j = n & 127;
    int half = j >> 6, r = j & 63;
    int e = (half == 0) ? (Cn + g * 64 + r) : (g * 64 + r);
    Gb[l][j] = bg[(b * Ln + l) * (2 * Cn) + e];
  }
  if (tid < Ln) B0[tid] = bias0[b * Ln + tid];
  __syncthreads();
  for (int i = 0; i < 32; ++i) {
    int n = i * 256 + tid;
    int m = n >> 6, kk = n & 63;
    float acc = 0.f;
#pragma unroll
    for (int l = 0; l < Ln; ++l) acc += Ms[l][kk] * Gb[l][m];
    unsigned off = (unsigned)((m * 128 + kk * 2) ^ ((m & 7) << 4));
    *(unsigned short*)(img + off) = f2bf(acc);
  }
  if (t == 0 && tid < 128) {
    float a = 0.f;
#pragma unroll
    for (int l = 0; l < Ln; ++l) a += B0[l] * Gb[l][tid];
    bv[b * 512 + g * 128 + tid] = a;
  }
  __syncthreads();
  unsigned long base = ((unsigned long)((b * 4 + g) * 4 + t)) * 16384ul;
  f32x4* dst = (f32x4*)((char*)Gt + base);
  const f32x4* srcv = (const f32x4*)img;
  for (int i = 0; i < 4; ++i) dst[i * 256 + tid] = srcv[i * 256 + tid];
}

// ---------------- kernel 5: instance-norm partials + h -> h_T (bf16) --------
__global__ void k_stats_tr(const float* __restrict__ h, unsigned short* __restrict__ hT,
                           float* __restrict__ part) {
  int hwc = blockIdx.x;  // 64 chunks of 256 hw
  int cc  = blockIdx.y;  // 4 chunks of 64 c
  int b   = blockIdx.z;
  int tid = threadIdx.x;
  int w = tid >> 6, lane = tid & 63;
  __shared__ unsigned short tile[64 * 258];  // [c][hw], rows padded to 258
  const int c0 = cc * 64, hw0 = hwc * 256;
  for (int i = 0; i < 16; ++i) {
    int cl = i * 4 + w;
    f32x4 v = *(const f32x4*)(h + ((unsigned long)(b * Cn + c0 + cl)) * HW + hw0 + lane * 4);
    float s  = v.x + v.y + v.z + v.w;
    float s2 = v.x * v.x + v.y * v.y + v.z * v.z + v.w * v.w;
#pragma unroll
    for (int o = 1; o < 64; o <<= 1) { s += __shfl_xor(s, o); s2 += __shfl_xor(s2, o); }
    if (lane == 0) {
      float* pp = part + (((unsigned long)(b * Cn + c0 + cl)) * 64 + hwc) * 2;
      pp[0] = s; pp[1] = s2;
    }
    unsigned lo = (unsigned)f2bf(v.x) | ((unsigned)f2bf(v.y) << 16);
    unsigned hi = (unsigned)f2bf(v.z) | ((unsigned)f2bf(v.w) << 16);
    unsigned* dst = (unsigned*)(tile + cl * 258 + lane * 4);
    dst[0] = lo; dst[1] = hi;
  }
  __syncthreads();
  for (int i = 0; i < 32; ++i) {
    int n = i * 256 + tid;
    int hw = n >> 5, cp = n & 31;
    unsigned short a0 = tile[(2 * cp) * 258 + hw];
    unsigned short a1 = tile[(2 * cp + 1) * 258 + hw];
    unsigned pk = (unsigned)a0 | ((unsigned)a1 << 16);
    *(unsigned*)(hT + ((unsigned long)b * HW + hw0 + hw) * Cn + c0 + 2 * cp) = pk;
  }
}

// ---------------- kernel 6: finalize stats -> scale/shift --------------------
__global__ void k_fin(const float* __restrict__ part, const float* __restrict__ inw,
                      const float* __restrict__ inb, float* __restrict__ ss) {
  int id = blockIdx.x * 256 + threadIdx.x;  // 4096 = B*C
  int c = id & 255;
  float s = 0.f, s2 = 0.f;
  const float* pp = part + (unsigned long)id * 128;
  for (int j = 0; j < 64; ++j) { s += pp[2 * j]; s2 += pp[2 * j + 1]; }
  float mean = s * (1.0f / HW);
  float var = s2 * (1.0f / HW) - mean * mean;
  float rs = rsqrtf(var + 1e-5f);
  float scv = rs * inw[c];
  float sh = inb[c] - mean * scv;
  ss[id * 2] = scv; ss[id * 2 + 1] = sh;
}

// ---------------- kernel 7: main fused GEMM + epilogue -----------------------
__global__ __launch_bounds__(256, 2) void k_main(
    const unsigned short* __restrict__ hT, const unsigned short* __restrict__ Gt,
    const float* __restrict__ bv, const float* __restrict__ ss,
    float* __restrict__ out) {
  int hwt = blockIdx.x, g = blockIdx.y, b = blockIdx.z;
  int hw0 = hwt * 128;
  int tid = threadIdx.x;
  int w = tid >> 6, lane = tid & 63;
  int wr = w >> 1, wc = w & 1;
  int lr = lane & 15, lg = lane >> 4;

  __shared__ __align__(16) unsigned char Ab[2][16384];
  __shared__ __align__(16) unsigned char Bb[2][16384];

  const unsigned long blobBase = ((unsigned long)(b * 4 + g)) * 4ul * 16384ul;
  const unsigned short* hTb = hT + (unsigned long)b * HW * Cn;

  f32x4 acc[4][4];
#pragma unroll
  for (int i = 0; i < 4; ++i)
#pragma unroll
    for (int j = 0; j < 4; ++j) acc[i][j] = (f32x4){0.f, 0.f, 0.f, 0.f};

  unsigned short h16[2][4][4];

  // prologue: stage chunk 0
#pragma unroll
  for (int j = 0; j < 4; ++j) {
    int seg = j * 4 + w;
    unsigned a = seg * 1024 + lane * 16;
    gl_lds16((const char*)Gt + blobBase + a, &Ab[0][seg * 1024]);
    int hwR = a >> 7, blk = (a >> 4) & 7;
    const void* src = (const char*)(hTb + (unsigned long)(hw0 + hwR) * Cn) +
                      ((blk ^ (hwR & 7)) * 16);
    gl_lds16(src, &Bb[0][seg * 1024]);
  }

#pragma unroll
  for (int t = 0; t < 4; ++t) {
    __syncthreads();
    int cur = t & 1;
    if (t < 3) {
      int tn = t + 1, nb = tn & 1;
#pragma unroll
      for (int j = 0; j < 4; ++j) {
        int seg = j * 4 + w;
        unsigned a = seg * 1024 + lane * 16;
        gl_lds16((const char*)Gt + blobBase + (unsigned long)tn * 16384ul + a, &Ab[nb][seg * 1024]);
        int hwR = a >> 7, blk = (a >> 4) & 7;
        const void* src = (const char*)(hTb + (unsigned long)(hw0 + hwR) * Cn + tn * 64) +
                          ((blk ^ (hwR & 7)) * 16);
        gl_lds16(src, &Bb[nb][seg * 1024]);
      }
    }
    if (t == g) {
      // snapshot h (bf16) for the epilogue: B chunk g holds c' = c_out range
#pragma unroll
      for (int p = 0; p < 2; ++p)
#pragma unroll
        for (int jn = 0; jn < 4; ++jn)
#pragma unroll
          for (int r = 0; r < 4; ++r) {
            int ki = wr * 32 + p * 16 + lg * 4 + r;
            int row = wc * 64 + jn * 16 + lr;
            unsigned off = (unsigned)((row * 128 + ki * 2) ^ ((row & 7) << 4));
            h16[p][jn][r] = *(const unsigned short*)(&Bb[cur][0] + off);
          }
    }
#pragma unroll
    for (int kk = 0; kk < 2; ++kk) {
      short8 afr[4], bfr[4];
#pragma unroll
      for (int jm = 0; jm < 4; ++jm) {
        int row = (jm >> 1) * 64 + wr * 32 + (jm & 1) * 16 + lr;
        unsigned off = (unsigned)((row * 128 + kk * 64 + lg * 16) ^ ((row & 7) << 4));
        afr[jm] = *(const short8*)(&Ab[cur][0] + off);
      }
#pragma unroll
      for (int jn = 0; jn < 4; ++jn) {
        int row = wc * 64 + jn * 16 + lr;
        unsigned off = (unsigned)((row * 128 + kk * 64 + lg * 16) ^ ((row & 7) << 4));
        bfr[jn] = *(const short8*)(&Bb[cur][0] + off);
      }
#pragma unroll
      for (int jm = 0; jm < 4; ++jm)
#pragma unroll
        for (int jn = 0; jn < 4; ++jn)
          acc[jm][jn] = __builtin_amdgcn_mfma_f32_16x16x32_bf16(afr[jm], bfr[jn], acc[jm][jn], 0, 0, 0);
    }
  }

  // epilogue: out = (h*sc+sh)*(accG+bvG) + (accB+bvB)
  const float* ssb = ss + (b * Cn) * 2;
  const float* bvb = bv + b * 512 + g * 128;
#pragma unroll
  for (int p = 0; p < 2; ++p) {
#pragma unroll
    for (int r = 0; r < 4; ++r) {
      int mloc = wr * 32 + p * 16 + lg * 4 + r;  // 0..63
      int cg = g * 64 + mloc;
      float scv = ssb[cg * 2], sh = ssb[cg * 2 + 1];
      float bvg = bvb[mloc];
      float bvbeta = bvb[64 + mloc];
#pragma unroll
      for (int jn = 0; jn < 4; ++jn) {
        float hv = bf2f(h16[p][jn][r]);
        float hn = hv * scv + sh;
        float gm = acc[p][jn][r] + bvg;
        float bt = acc[2 + p][jn][r] + bvbeta;
        int hwg = hw0 + wc * 64 + jn * 16 + lr;
        out[((unsigned long)(b * Cn + cg)) * HW + hwg] = hn * gm + bt;
      }
    }
  }
}

__global__ void k_sentinel(float* out) { out[0] = 12345.0f; }

// ---------------- launcher ---------------------------------------------------
extern "C" void kernel_launch(void* const* d_in, const int* in_sizes, int n_in,
                              void* d_out, int out_size, void* d_ws, size_t ws_size,
                              hipStream_t stream) {
  const float* wsrc   = (const float*)d_in[0];
  const float* wtgt   = (const float*)d_in[1];
  const float* h      = (const float*)d_in[2];
  const float* conv0w = (const float*)d_in[3];
  const float* conv0b = (const float*)d_in[4];
  const float* fckw   = (const float*)d_in[5];
  const float* fckb   = (const float*)d_in[6];
  const float* fcw    = (const float*)d_in[7];
  const float* fcb    = (const float*)d_in[8];
  const float* inw    = (const float*)d_in[9];
  const float* inb    = (const float*)d_in[10];
  float* out = (float*)d_out;
  char* ws = (char*)d_ws;

  const size_t NEED = 142542848ull;
  if (ws_size < NEED) {  // distinctive failure signature instead of OOB writes
    k_sentinel<<<1, 1, 0, stream>>>(out);
    return;
  }

  unsigned short* hT = (unsigned short*)(ws + 0);           // 134217728
  float* kmat   = (float*)(ws + 134217728);                 // 393216
  float* walloc = (float*)(ws + 134610944);                 // 393216
  float* bias0  = (float*)(ws + 135004160);                 // 2048
  float* bg     = (float*)(ws + 135006208);                 // 786432
  float* Mmat   = (float*)(ws + 135792640);                 // 393216
  unsigned short* Gt = (unsigned short*)(ws + 136185856);   // 4194304
  float* bv     = (float*)(ws + 140380160);                 // 32768
  float* part   = (float*)(ws + 140412928);                 // 2097152
  float* ss     = (float*)(ws + 142510080);                 // 32768

  k_keys<<<Bn * Ln, 256, 0, stream>>>(wsrc, fckw, fckb, kmat);
  k_alloc<<<Bn, 256, 0, stream>>>(wsrc, wtgt, conv0b, kmat, walloc, bias0);
  k_mbg<<<2 * Bn * Ln, 256, 0, stream>>>(kmat, conv0w, walloc, fcw, fcb, Mmat, bg);
  dim3 gg(4, 4, Bn);
  k_gbuild<<<gg, 256, 0, stream>>>(Mmat, bg, bias0, Gt, bv);
  dim3 gs(64, 4, Bn);
  k_stats_tr<<<gs, 256, 0, stream>>>(h, hT, part);
  k_fin<<<16, 256, 0, stream>>>(part, inw, inb, ss);
  dim3 gm(128, 4, Bn);
  k_main<<<gm, 256, 0, stream>>>(hT, Gt, bv, ss, out);
}